// Round 10
// baseline (103.898 us; speedup 1.0000x reference)
//
#include <hip/hip_runtime.h>
#include <hip/hip_bf16.h>

// LocallyConnected2d: B=16, C=32, O=32, H=W=64, K=3x3, pad=1, stride=1.
// out[b,o,h,w] = sum_{c,k} x[b,c,h+dh,w+dw] * weight[o,c,h,w,k]
//
// R10: R9 structure (weight read ONCE: BB=16, no batch split; linear
// global_load_lds weight staging; bf16 x-window) with the overlap fixed:
//  - OO=2 -> 1024 blocks = 4 blocks/CU, 4 waves/SIMD (R9 had 512/2/2: the
//    per-c vmcnt(0) drain had nothing to hide under).
//  - stage TWO c's per drain (2-slot LDS, 36.9KB total, 4 blocks/CU exact
//    fit at 147/160KB): 4 drains/kernel, each amortized over ~2x compute.
//  - private per-wave LDS slots, no barriers; 4 atomic addends per output.

#define CIN  32
#define OCH  32
#define HH   64
#define WW   64
#define HW   4096
#define BB   16    // ALL batches per thread -> weight stream not duplicated
#define OO   2     // output channels per thread
#define CC   8     // input channels per block (c-split 4)
#define XWR  66    // padded rows in XW

typedef float f32x4 __attribute__((ext_vector_type(4), aligned(16)));
typedef unsigned int u32x2 __attribute__((ext_vector_type(2), aligned(8)));

typedef const __attribute__((address_space(1))) unsigned int* gptr1_t;
typedef __attribute__((address_space(3))) unsigned int* lptr3_t;

__device__ __forceinline__ void stage16(const void* g, void* l) {
    __builtin_amdgcn_global_load_lds((gptr1_t)(unsigned long long)g,
                                     (lptr3_t)(unsigned int)(unsigned long long)l,
                                     16, 0, 0);
}
__device__ __forceinline__ void stage4(const void* g, void* l) {
    __builtin_amdgcn_global_load_lds((gptr1_t)(unsigned long long)g,
                                     (lptr3_t)(unsigned int)(unsigned long long)l,
                                     4, 0, 0);
}

__device__ __forceinline__ unsigned short f2bf(float f) {
    unsigned u = __float_as_uint(f);
    u += 0x7fffu + ((u >> 16) & 1u);
    return (unsigned short)(u >> 16);
}
__device__ __forceinline__ float bf_lo(unsigned v) { return __uint_as_float(v << 16); }
__device__ __forceinline__ float bf_hi(unsigned v) { return __uint_as_float(v & 0xffff0000u); }

__global__ __launch_bounds__(256)
void zero_out_kernel(float* __restrict__ out, int n4) {
    int i = blockIdx.x * 256 + threadIdx.x;
    if (i < n4) ((f32x4*)out)[i] = (f32x4){0.f, 0.f, 0.f, 0.f};
}

// XW[b][c][66][64] : ushort4{bf16 x[w-1], bf16 x[w], bf16 x[w+1], 0};
// rows 0/65 zero (vertical pad), w edges zero.
__global__ __launch_bounds__(256)
void xwin_kernel(const float* __restrict__ x, u32x2* __restrict__ xw) {
    int tid = blockIdx.x * 256 + threadIdx.x;
    const int total = 16 * CIN * XWR * 64;
    if (tid >= total) return;
    const int w  = tid & 63;
    const int r  = (tid >> 6) % XWR;
    const int bc = tid / (XWR * 64);
    const int h  = r - 1;
    float xl = 0.f, xm = 0.f, xr = 0.f;
    if (h >= 0 && h < HH) {
        const float* row = x + (size_t)bc * HW + (size_t)h * WW;
        xl = (w > 0)      ? row[w - 1] : 0.f;
        xm = row[w];
        xr = (w < WW - 1) ? row[w + 1] : 0.f;
    }
    u32x2 v;
    v.x = (unsigned)f2bf(xl) | ((unsigned)f2bf(xm) << 16);
    v.y = (unsigned)f2bf(xr);
    xw[tid] = v;
}

template<bool XWOK>
__global__ __launch_bounds__(256)
void lc2d_kernel(const float* __restrict__ x, const float* __restrict__ wt,
                 const u32x2* __restrict__ xw, float* __restrict__ out) {
    // [slot][ty][oo][576 floats] = 2*4*2*576*4B = 36864 B
    __shared__ float smem[2][4][OO][576];
    const int w  = threadIdx.x;                 // lane == w
    const int ty = threadIdx.y;
    const int h  = blockIdx.x * 4 + ty;
    const int o0 = blockIdx.y * OO;
    const int cg = blockIdx.z;
    const int c0 = cg * CC;

    // fallback-only edge handling
    const float mt = (h > 0) ? 1.f : 0.f, mb = (h < HH - 1) ? 1.f : 0.f;
    const float ml = (w > 0) ? 1.f : 0.f, mr = (w < WW - 1) ? 1.f : 0.f;
    const int iht = (h > 0) ? h - 1 : 0, ihb = (h < HH - 1) ? h + 1 : HH - 1;
    const int cl = (w > 0) ? w - 1 : 0, cr = (w < WW - 1) ? w + 1 : WW - 1;

    float acc[OO][BB];
#pragma unroll
    for (int oo = 0; oo < OO; ++oo)
#pragma unroll
        for (int b = 0; b < BB; ++b) acc[oo][b] = 0.f;

    // stage one c's weight rows (2304B contiguous per oo) into LDS slot
    auto stage_c = [&](int cc, int slot) {
#pragma unroll
        for (int oo = 0; oo < OO; ++oo) {
            const char* src = (const char*)wt
                + ((size_t)(o0 + oo) * CIN + cc) * ((size_t)HW * 36)
                + (size_t)h * 2304;
            float* lb = &smem[slot][ty][oo][0];
            stage16(src + (size_t)w * 16,        lb);
            stage16(src + 1024 + (size_t)w * 16, lb + 256);
            stage4 (src + 2048 + (size_t)w * 4,  lb + 512);
        }
    };

    for (int j = 0; j < CC / 2; ++j) {
        // stage a PAIR of c's, then one drain for both
        stage_c(c0 + 2 * j,     0);
        stage_c(c0 + 2 * j + 1, 1);
        __builtin_amdgcn_s_waitcnt(0);

#pragma unroll
        for (int s = 0; s < 2; ++s) {
            const int cc = c0 + 2 * j + s;

            // per-lane weights from LDS (stride-9 dwords: 2-way max = free)
            float wk[OO][9];
#pragma unroll
            for (int oo = 0; oo < OO; ++oo) {
                const float* wp = &smem[s][ty][oo][0] + w * 9;
#pragma unroll
                for (int k = 0; k < 9; ++k) wk[oo][k] = wp[k];
            }
            if (!XWOK) {
#pragma unroll
                for (int oo = 0; oo < OO; ++oo) {
                    wk[oo][0] *= mt * ml; wk[oo][1] *= mt; wk[oo][2] *= mt * mr;
                    wk[oo][3] *= ml;                        wk[oo][5] *= mr;
                    wk[oo][6] *= mb * ml; wk[oo][7] *= mb; wk[oo][8] *= mb * mr;
                }
            }

            size_t xwi = (size_t)cc * (XWR * 64) + (size_t)h * 64 + w;
#pragma unroll
            for (int b = 0; b < BB; ++b) {
                float t0, t1, t2, t3, t4, t5, t6, t7, t8;
                if (XWOK) {
                    const u32x2 r0 = xw[xwi];
                    const u32x2 r1 = xw[xwi + 64];
                    const u32x2 r2 = xw[xwi + 128];
                    t0 = bf_lo(r0.x); t1 = bf_hi(r0.x); t2 = bf_lo(r0.y);
                    t3 = bf_lo(r1.x); t4 = bf_hi(r1.x); t5 = bf_lo(r1.y);
                    t6 = bf_lo(r2.x); t7 = bf_hi(r2.x); t8 = bf_lo(r2.y);
                    xwi += (size_t)CIN * XWR * 64;
                } else {
                    const float* xp = x + ((size_t)b * CIN + cc) * HW;
                    const float* r0 = xp + iht * WW;
                    const float* r1 = xp + h * WW;
                    const float* r2 = xp + ihb * WW;
                    t0 = r0[cl]; t1 = r0[w]; t2 = r0[cr];
                    t3 = r1[cl]; t4 = r1[w]; t5 = r1[cr];
                    t6 = r2[cl]; t7 = r2[w]; t8 = r2[cr];
                }
#pragma unroll
                for (int oo = 0; oo < OO; ++oo) {
                    float a = acc[oo][b];
                    a = fmaf(t0, wk[oo][0], a); a = fmaf(t1, wk[oo][1], a);
                    a = fmaf(t2, wk[oo][2], a); a = fmaf(t3, wk[oo][3], a);
                    a = fmaf(t4, wk[oo][4], a); a = fmaf(t5, wk[oo][5], a);
                    a = fmaf(t6, wk[oo][6], a); a = fmaf(t7, wk[oo][7], a);
                    a = fmaf(t8, wk[oo][8], a);
                    acc[oo][b] = a;
                }
            }
        }
    }

#pragma unroll
    for (int b = 0; b < BB; ++b)
#pragma unroll
        for (int oo = 0; oo < OO; ++oo)
            atomicAdd(out + (((size_t)b * OCH + (o0 + oo)) * HH + h) * WW + w,
                      acc[oo][b]);
}

extern "C" void kernel_launch(void* const* d_in, const int* in_sizes, int n_in,
                              void* d_out, int out_size, void* d_ws, size_t ws_size,
                              hipStream_t stream) {
    const float* x  = (const float*)d_in[0];
    const float* wt = (const float*)d_in[1];
    float* out = (float*)d_out;

    const int n4 = out_size / 4;
    zero_out_kernel<<<(n4 + 255) / 256, 256, 0, stream>>>(out, n4);

    const size_t ws_need = (size_t)16 * CIN * XWR * 64 * 8;   // 17.3 MB
    dim3 block(64, 4);
    dim3 grid(HH / 4, OCH / OO, 4);   // 16 x 16 x 4 = 1024 blocks

    if (ws_size >= ws_need) {
        u32x2* xw = (u32x2*)d_ws;
        const int total = 16 * CIN * XWR * 64;
        xwin_kernel<<<(total + 255) / 256, 256, 0, stream>>>(x, xw);
        lc2d_kernel<true><<<grid, block, 0, stream>>>(x, wt, xw, out);
    } else {
        lc2d_kernel<false><<<grid, block, 0, stream>>>(x, wt, (const u32x2*)d_ws, out);
    }
}